// Round 15
// baseline (117.577 us; speedup 1.0000x reference)
//
#include <hip/hip_runtime.h>
#include <hip/hip_bf16.h>
#include <math.h>

#define BATCH 512
#define EMBED 512
#define NCLS  100000
#define NT128 782          // ceil(100000/128) class tiles
#define NBLK  256          // kmain: 2 panels x 128 cgs

typedef __attribute__((ext_vector_type(4)))  float f32x4;
typedef __attribute__((ext_vector_type(16))) float f32x16;
typedef __attribute__((ext_vector_type(2)))  long  i64x2;

constexpr float kCOS_M = 0.8775825618903728f;   // cos(0.5)
constexpr float kSIN_M = 0.4794255386042030f;   // sin(0.5)
constexpr float kTHR   = -0.8775825618903728f;  // cos(pi-0.5)
constexpr float kMM    = 0.2397127693021015f;   // sin(pi-0.5)*0.5

#define BARRIER() asm volatile("s_waitcnt lgkmcnt(0)\n\ts_barrier" ::: "memory")
#define VMW2() asm volatile("s_waitcnt vmcnt(2)" ::: "memory")
#define VMW0() asm volatile("s_waitcnt vmcnt(0)" ::: "memory")

__device__ __forceinline__ unsigned cvt4(float a, float b, float c, float d) {
  int v = __builtin_amdgcn_cvt_pk_fp8_f32(a, b, 0, false);
  v = __builtin_amdgcn_cvt_pk_fp8_f32(c, d, v, true);
  return (unsigned)v;
}

// ---------------- K1: normalize embeddings -> fp8 x16, hi-split + XOR-swizzled ----
// (R11 verbatim) Element k of row r: slotL = k[3]<<4 | k[8:5], half = k[4];
// physical 16B slot = slotL ^ (r&31); byte = half*8 + k[2:0].
__global__ void knorm_e(const float* __restrict__ E, unsigned char* __restrict__ E8) {
  int r = blockIdx.x;
  int l = threadIdx.x;                       // lane owns elems 8l..8l+7
  const f32x4* src = (const f32x4*)(E + r * EMBED);
  f32x4 a = src[2 * l], b = src[2 * l + 1];
  float ss = a.x*a.x + a.y*a.y + a.z*a.z + a.w*a.w
           + b.x*b.x + b.y*b.y + b.z*b.z + b.w*b.w;
#pragma unroll
  for (int d = 1; d < 64; d <<= 1) ss += __shfl_xor(ss, d);
  float s = 16.0f / fmaxf(sqrtf(ss), 1e-12f);
  uint2 pk;
  pk.x = cvt4(a.x * s, a.y * s, a.z * s, a.w * s);
  pk.y = cvt4(b.x * s, b.y * s, b.z * s, b.w * s);
  int slotL = (l & 1) * 16 + (l >> 2);
  int half  = (l >> 1) & 1;
  *(uint2*)(E8 + r * 512 + (((slotL ^ (r & 31)) << 4) | (half << 3))) = pk;
}

// ---------------- K2: label-column cosine + margin in f32 ----------------
__global__ void klabel(const float* __restrict__ E, const float* __restrict__ W,
                       const int* __restrict__ labels,
                       float* __restrict__ lcos, float* __restrict__ lphi)
{
  int r = blockIdx.x * 8 + (threadIdx.x >> 6);
  int l = threadIdx.x & 63;
  int lbl = labels[r];
  const float* ep = E + (size_t)r * EMBED + l * 8;
  const float* wp = W + (size_t)lbl * EMBED + l * 8;
  f32x4 e0 = *(const f32x4*)ep, e1 = *(const f32x4*)(ep + 4);
  f32x4 w0 = *(const f32x4*)wp, w1 = *(const f32x4*)(wp + 4);
  float dot = e0.x*w0.x + e0.y*w0.y + e0.z*w0.z + e0.w*w0.w
            + e1.x*w1.x + e1.y*w1.y + e1.z*w1.z + e1.w*w1.w;
  float se = e0.x*e0.x + e0.y*e0.y + e0.z*e0.z + e0.w*e0.w
           + e1.x*e1.x + e1.y*e1.y + e1.z*e1.z + e1.w*e1.w;
  float sw = w0.x*w0.x + w0.y*w0.y + w0.z*w0.z + w0.w*w0.w
           + w1.x*w1.x + w1.y*w1.y + w1.z*w1.z + w1.w*w1.w;
#pragma unroll
  for (int d = 1; d < 64; d <<= 1) {
    dot += __shfl_xor(dot, d); se += __shfl_xor(se, d); sw += __shfl_xor(sw, d);
  }
  float cosv = dot / (fmaxf(sqrtf(se), 1e-12f) * fmaxf(sqrtf(sw), 1e-12f));
  float cc = fminf(fmaxf(cosv, -1.f), 1.f);
  float sine = sqrtf(fmaxf(1.f - cc * cc, 0.f));
  float phi = (cosv > kTHR) ? (cosv * kCOS_M - sine * kSIN_M) : (cosv - kMM);
  if (l == 0) { lcos[r] = 64.f * cosv; lphi[r] = 64.f * phi; }
}

// ---------------- K3: W -> fp8 pre-conversion + per-(class,kq) sumsq -------
// Block = one (tile, kq) 8KB output chunk, 1024 threads: thread (cls=tid>>3,
// bs3=tid&7) reads 8 consecutive f32 of W, writes one uint2 into the chunk at
// EXACTLY kmain's Bsm byte layout -> kmain stages with pure linear glds.
__global__ __launch_bounds__(1024) void kconv(
    const float* __restrict__ W, unsigned char* __restrict__ W8,
    float* __restrict__ rowsumP)
{
  int blk = blockIdx.x;                 // 0..6255
  int tile = blk >> 3, kq = blk & 7;
  int tid = threadIdx.x;
  int cls = tid >> 3, bs3 = tid & 7;
  int clsg = tile * 128 + cls;
  bool valid = clsg < NCLS;
  const float* p = W + (size_t)(valid ? clsg : (NCLS - 1)) * EMBED + kq * 64 + bs3 * 8;
  f32x4 v0 = *(const f32x4*)p;
  f32x4 v1 = *(const f32x4*)(p + 4);
  float x0 = v0.x*128.f, x1 = v0.y*128.f, x2 = v0.z*128.f, x3 = v0.w*128.f;
  float x4 = v1.x*128.f, x5 = v1.y*128.f, x6 = v1.z*128.f, x7 = v1.w*128.f;
  if (!valid) { x0=x1=x2=x3=x4=x5=x6=x7=0.f; }
  float ssq = x0*x0 + x1*x1 + x2*x2 + x3*x3 + x4*x4 + x5*x5 + x6*x6 + x7*x7;
  uint2 pk;
  pk.x = cvt4(x0, x1, x2, x3);
  pk.y = cvt4(x4, x5, x6, x7);
  int boffA = (cls >> 6) * 4096 + ((bs3 & 1) * 2 + (bs3 >> 2)) * 1024
            + (cls & 63) * 16 + ((bs3 >> 1) & 1) * 8;
  *(uint2*)(W8 + (size_t)tile * 65536 + kq * 8192 + boffA) = pk;
  // reduce ssq over the 8 bs3 lanes of this class (lane group 8-aligned)
  ssq += __shfl_xor(ssq, 1); ssq += __shfl_xor(ssq, 2); ssq += __shfl_xor(ssq, 4);
  if (bs3 == 0 && valid) rowsumP[(size_t)clsg * 8 + kq] = ssq;
}

// ---------------- K4: fused fp8 GEMM + fixed-max expsum (lean) -------------
// 256 blocks (1/CU) = 2 panels x 128 cgs, panel-siblings same XCD. A panel
// (256x512 fp8, R11 layout) LDS-resident. B: 8KB/phase staged by LINEAR
// global_load_lds from W8 into a ring of 4 buffers; glds issued 3 phases
// ahead; counted vmcnt(2) before each barrier (never drained in-loop).
// No cvt/ssq in the loop: rowsums precomputed by kconv.
__global__ __launch_bounds__(1024, 4) void kmain(
    const unsigned char* __restrict__ E8, const unsigned char* __restrict__ W8,
    const float* __restrict__ rowsumP, float* __restrict__ psum)
{
  __shared__ __align__(16) unsigned char SH[163840];
  unsigned char* Asm = SH;                         // 131072 B
  unsigned char* Bb0 = SH + 131072;                // 4 x 8192 B ring
  unsigned char* Bb1 = SH + 131072 + 8192;
  unsigned char* Bb2 = SH + 131072 + 16384;
  unsigned char* Bb3 = SH + 131072 + 24576;

  int bid = blockIdx.x;
  int xcd = bid & 7;
  int panel = (bid >> 3) & 1;
  int grp = bid >> 4;                        // 0..15
  int cg = xcd | (grp << 3);                 // 0..127

  int tid = threadIdx.x;
  int w = tid >> 6, l = tid & 63;
  int wr = w >> 1, wc = w & 1;               // 8 row-waves x 2 col-waves
  int cl = l & 31, hi = l >> 5;

  int nt = (cg < 14) ? 7 : 6;                // 782 = 6*128 + 14
  int nph = nt * 8;

  // ---- stage A panel once (R11 layout, source pre-swizzled) ----
#pragma unroll
  for (int i = 0; i < 8; ++i) {
    int base = i * 16384 + w * 1024;
    __builtin_amdgcn_global_load_lds(
        (const __attribute__((address_space(1))) void*)(E8 + panel * 131072 + base + l * 16),
        (__attribute__((address_space(3))) void*)(&Asm[base]), 16, 0, 0);
  }

  // ---- B staging: waves 0-7 copy 8KB linearly ----
  auto gldsB = [&](unsigned char* buf, int q) {
    if (tid < 512) {
      const unsigned char* src = W8 + (size_t)(cg + ((q >> 3) << 7)) * 65536
                               + (q & 7) * 8192 + tid * 16;
      __builtin_amdgcn_global_load_lds(
          (const __attribute__((address_space(1))) void*)src,
          (__attribute__((address_space(3))) void*)(buf + tid * 16), 16, 0, 0);
    }
  };

  f32x16 acc0, acc1, S;
#pragma unroll
  for (int e = 0; e < 16; ++e) { acc0[e] = 0.f; acc1[e] = 0.f; S[e] = 0.f; }

  const unsigned char* Abase = Asm + (wr * 32 + cl) * 512;
  const int bcol = wc * 4096 + hi * 2048 + cl * 16;
  const unsigned char* Bc0 = Bb0 + bcol;
  const unsigned char* Bc1 = Bb1 + bcol;
  const unsigned char* Bc2 = Bb2 + bcol;
  const unsigned char* Bc3 = Bb3 + bcol;

  auto compute = [&](const unsigned char* bb, int pt) {
    int t0 = pt * 2;
    i64x2 a0 = *(const i64x2*)(Abase + ((((hi << 4) | t0)       ^ cl) << 4));
    i64x2 a1 = *(const i64x2*)(Abase + ((((hi << 4) | (t0 + 1)) ^ cl) << 4));
    i64x2 b0 = *(const i64x2*)(bb);
    i64x2 b1 = *(const i64x2*)(bb + 1024);
    i64x2 c0 = *(const i64x2*)(bb + 512);
    i64x2 c1 = *(const i64x2*)(bb + 1536);
    __builtin_amdgcn_s_setprio(1);
    acc0 = __builtin_amdgcn_mfma_f32_32x32x16_fp8_fp8(a0[0], b0[0], acc0, 0, 0, 0);
    acc0 = __builtin_amdgcn_mfma_f32_32x32x16_fp8_fp8(a0[1], b0[1], acc0, 0, 0, 0);
    acc0 = __builtin_amdgcn_mfma_f32_32x32x16_fp8_fp8(a1[0], b1[0], acc0, 0, 0, 0);
    acc0 = __builtin_amdgcn_mfma_f32_32x32x16_fp8_fp8(a1[1], b1[1], acc0, 0, 0, 0);
    acc1 = __builtin_amdgcn_mfma_f32_32x32x16_fp8_fp8(a0[0], c0[0], acc1, 0, 0, 0);
    acc1 = __builtin_amdgcn_mfma_f32_32x32x16_fp8_fp8(a0[1], c0[1], acc1, 0, 0, 0);
    acc1 = __builtin_amdgcn_mfma_f32_32x32x16_fp8_fp8(a1[0], c1[0], acc1, 0, 0, 0);
    acc1 = __builtin_amdgcn_mfma_f32_32x32x16_fp8_fp8(a1[1], c1[1], acc1, 0, 0, 0);
    __builtin_amdgcn_s_setprio(0);
  };

  f32x4 Rr0a, Rr0b, Rr1a, Rr1b;
  auto loadRS = [&](int T) {
    int base = (cg + (T << 7)) * 128 + wc * 64;
    const float* rp0 = rowsumP + (size_t)(base + cl) * 8;
    const float* rp1 = rowsumP + (size_t)(base + 32 + cl) * 8;
    Rr0a = *(const f32x4*)rp0; Rr0b = *(const f32x4*)(rp0 + 4);
    Rr1a = *(const f32x4*)rp1; Rr1b = *(const f32x4*)(rp1 + 4);
  };
  auto epilogue = [&](int T) {
    float rs0 = Rr0a.x + Rr0a.y + Rr0a.z + Rr0a.w + Rr0b.x + Rr0b.y + Rr0b.z + Rr0b.w;
    float rs1 = Rr1a.x + Rr1a.y + Rr1a.z + Rr1a.w + Rr1b.x + Rr1b.y + Rr1b.z + Rr1b.w;
    float rn0 = 4.0f / sqrtf(fmaxf(rs0, 1e-30f));
    float rn1 = 4.0f / sqrtf(fmaxf(rs1, 1e-30f));
    int base = (cg + (T << 7)) * 128 + wc * 64;
    float vm0 = (base + cl < NCLS) ? 1.0f : 0.0f;
    float vm1 = (base + 32 + cl < NCLS) ? 1.0f : 0.0f;
#pragma unroll
    for (int e = 0; e < 16; ++e) {
      float u0 = __expf(fmaf(acc0[e], rn0, -64.0f));
      float u1 = __expf(fmaf(acc1[e], rn1, -64.0f));
      S[e] = fmaf(u0, vm0, fmaf(u1, vm1, S[e]));
      acc0[e] = 0.f; acc1[e] = 0.f;
    }
  };

  // ---- prologue: A + B phases 0,1,2 staged; drain once; barrier ----
  gldsB(Bb0, 0); gldsB(Bb1, 1); gldsB(Bb2, 2);
  VMW0();
  BARRIER();

#define PH(p, BCOL, BGLDS) {                                   \
    compute(BCOL, (p) & 7);                                    \
    if (((p) & 7) == 6) loadRS((p) >> 3);                      \
    bool more = ((p) + 3 < nph);                               \
    if (more) gldsB(BGLDS, (p) + 3);                           \
    if (((p) & 7) == 7) epilogue((p) >> 3);                    \
    if (more) { VMW2(); } else { VMW0(); }                     \
    BARRIER();                                                 \
  }

  for (int pb = 0; pb < nph; pb += 4) {
    PH(pb + 0, Bc0, Bb3)
    PH(pb + 1, Bc1, Bb0)
    PH(pb + 2, Bc2, Bb1)
    PH(pb + 3, Bc3, Bb2)
  }
#undef PH

  // ---- fold S across the 32 class-lanes; write per-col-wave partials ----
#pragma unroll
  for (int e = 0; e < 16; ++e) {
    float v = S[e];
    v += __shfl_xor(v, 1); v += __shfl_xor(v, 2); v += __shfl_xor(v, 4);
    v += __shfl_xor(v, 8); v += __shfl_xor(v, 16);
    S[e] = v;
  }
  if (cl == 0) {
#pragma unroll
    for (int e = 0; e < 16; ++e) {
      int row = wr * 32 + (e & 3) + 8 * (e >> 2) + 4 * hi;
      psum[bid * 512 + wc * 256 + row] = S[e];
    }
  }
}

// ---------------- K5: final combine + label adjust + NLL mean ----------------
__global__ void kfinal(const float* __restrict__ psum, const float* __restrict__ lcos,
                       const float* __restrict__ lphi, float* __restrict__ out)
{
  int tid = threadIdx.x;         // 512 = one thread per batch row
  int panel = tid >> 8, rl = tid & 255;
  float S = 0.f;
#pragma unroll
  for (int grp = 0; grp < 16; ++grp) {
#pragma unroll
    for (int x = 0; x < 8; ++x) {
      int b = x | (panel << 3) | (grp << 4);
      S += psum[b * 512 + rl] + psum[b * 512 + 256 + rl];
    }
  }
  float lc = lcos[tid], lp = lphi[tid];
  S = S - __expf(lc - 64.f) + __expf(lp - 64.f);
  float nll = 64.f + __logf(S) - lp;
#pragma unroll
  for (int d = 1; d < 64; d <<= 1) nll += __shfl_xor(nll, d);
  __shared__ float sm[8];
  if ((tid & 63) == 0) sm[tid >> 6] = nll;
  __syncthreads();
  if (tid == 0) {
    float t = 0.f;
    for (int k = 0; k < 8; ++k) t += sm[k];
    out[0] = t * (1.0f / 512.0f);
  }
}

extern "C" void kernel_launch(void* const* d_in, const int* in_sizes, int n_in,
                              void* d_out, int out_size, void* d_ws, size_t ws_size,
                              hipStream_t stream)
{
  const float* E      = (const float*)d_in[0];
  const int*   labels = (const int*)d_in[1];
  const float* W      = (const float*)d_in[2];
  float* out = (float*)d_out;

  char* ws = (char*)d_ws;
  unsigned char* E8 = (unsigned char*)ws;               // 262144 B
  unsigned char* W8 = (unsigned char*)(ws + 262144);    // 782*65536 = 51249152 B
  float* rowsumP = (float*)(ws + 262144 + 51249152);    // 782*128*8*4 = 3203072 B
  float* psum    = (float*)(ws + 262144 + 51249152 + 3203072);  // 256*512*4 = 524288 B
  float* lcos    = (float*)(ws + 262144 + 51249152 + 3203072 + 524288);  // 2048 B
  float* lphi    = lcos + BATCH;                        // 2048 B

  knorm_e<<<BATCH, 64, 0, stream>>>(E, E8);
  klabel <<<64, 512, 0, stream>>>(E, W, labels, lcos, lphi);
  kconv  <<<NT128 * 8, 1024, 0, stream>>>(W, W8, rowsumP);
  kmain  <<<NBLK, 1024, 0, stream>>>(E8, W8, rowsumP, psum);
  kfinal <<<1, 512, 0, stream>>>(psum, lcos, lphi, out);
}

// Round 16
// 80.786 us; speedup vs baseline: 1.4554x; 1.4554x over previous
//
#include <hip/hip_runtime.h>
#include <hip/hip_bf16.h>
#include <math.h>

#define BATCH 512
#define EMBED 512
#define NCLS  100000
#define NT128 782          // ceil(100000/128) class tiles of 128
#define NCG   128          // column groups
#define NBLK  256          // 2 panels x 128 cgs

typedef __attribute__((ext_vector_type(4)))  float f32x4;
typedef __attribute__((ext_vector_type(16))) float f32x16;
typedef __attribute__((ext_vector_type(2)))  long  i64x2;

constexpr float kCOS_M = 0.8775825618903728f;   // cos(0.5)
constexpr float kSIN_M = 0.4794255386042030f;   // sin(0.5)
constexpr float kTHR   = -0.8775825618903728f;  // cos(pi-0.5)
constexpr float kMM    = 0.2397127693021015f;   // sin(pi-0.5)*0.5

#define BARRIER() asm volatile("s_waitcnt lgkmcnt(0)\n\ts_barrier" ::: "memory")

__device__ __forceinline__ unsigned cvt4(float a, float b, float c, float d) {
  int v = __builtin_amdgcn_cvt_pk_fp8_f32(a, b, 0, false);
  v = __builtin_amdgcn_cvt_pk_fp8_f32(c, d, v, true);
  return (unsigned)v;
}

// ---------------- K1: normalize embeddings -> fp8 x16, hi-split + XOR-swizzled ----
// Element k of row r: slotL = k[3]<<4 | k[8:5], half = k[4];
// physical 16B slot = slotL ^ (r&31); byte = half*8 + k[2:0].
__global__ void knorm_e(const float* __restrict__ E, unsigned char* __restrict__ En8) {
  int r = blockIdx.x;
  int l = threadIdx.x;                       // lane owns elems 8l..8l+7
  const f32x4* src = (const f32x4*)(E + r * EMBED);
  f32x4 a = src[2 * l], b = src[2 * l + 1];
  float ss = a.x*a.x + a.y*a.y + a.z*a.z + a.w*a.w
           + b.x*b.x + b.y*b.y + b.z*b.z + b.w*b.w;
#pragma unroll
  for (int d = 1; d < 64; d <<= 1) ss += __shfl_xor(ss, d);
  float s = 16.0f / fmaxf(sqrtf(ss), 1e-12f);
  uint2 pk;
  pk.x = cvt4(a.x * s, a.y * s, a.z * s, a.w * s);
  pk.y = cvt4(b.x * s, b.y * s, b.z * s, b.w * s);
  int slotL = (l & 1) * 16 + (l >> 2);
  int half  = (l >> 1) & 1;
  *(uint2*)(En8 + r * 512 + (((slotL ^ (r & 31)) << 4) | (half << 3))) = pk;
}

// ---------------- K2: label-column cosine + margin in f32 ----------------
__global__ void klabel(const float* __restrict__ E, const float* __restrict__ W,
                       const int* __restrict__ labels,
                       float* __restrict__ lcos, float* __restrict__ lphi)
{
  int r = blockIdx.x * 8 + (threadIdx.x >> 6);
  int l = threadIdx.x & 63;
  int lbl = labels[r];
  const float* ep = E + (size_t)r * EMBED + l * 8;
  const float* wp = W + (size_t)lbl * EMBED + l * 8;
  f32x4 e0 = *(const f32x4*)ep, e1 = *(const f32x4*)(ep + 4);
  f32x4 w0 = *(const f32x4*)wp, w1 = *(const f32x4*)(wp + 4);
  float dot = e0.x*w0.x + e0.y*w0.y + e0.z*w0.z + e0.w*w0.w
            + e1.x*w1.x + e1.y*w1.y + e1.z*w1.z + e1.w*w1.w;
  float se = e0.x*e0.x + e0.y*e0.y + e0.z*e0.z + e0.w*e0.w
           + e1.x*e1.x + e1.y*e1.y + e1.z*e1.z + e1.w*e1.w;
  float sw = w0.x*w0.x + w0.y*w0.y + w0.z*w0.z + w0.w*w0.w
           + w1.x*w1.x + w1.y*w1.y + w1.z*w1.z + w1.w*w1.w;
#pragma unroll
  for (int d = 1; d < 64; d <<= 1) {
    dot += __shfl_xor(dot, d); se += __shfl_xor(se, d); sw += __shfl_xor(sw, d);
  }
  float cosv = dot / (fmaxf(sqrtf(se), 1e-12f) * fmaxf(sqrtf(sw), 1e-12f));
  float cc = fminf(fmaxf(cosv, -1.f), 1.f);
  float sine = sqrtf(fmaxf(1.f - cc * cc, 0.f));
  float phi = (cosv > kTHR) ? (cosv * kCOS_M - sine * kSIN_M) : (cosv - kMM);
  if (l == 0) { lcos[r] = 64.f * cosv; lphi[r] = 64.f * phi; }
}

// ---------------- K3: fused fp8 GEMM + fixed-max expsum (R11) --------------
// BM=256, B-tile=128 classes/phase. 256 blocks (1/CU) = 2 panels x 128 cgs.
// A panel (256x512 fp8 = 128KB) LDS-resident. Waves: 8 row x 2 col, each
// 32 rows x 64 classes (acc0/acc1). One barrier per phase, write p+2 after
// the barrier ending p's reads, loads 4 phases ahead.
__global__ __launch_bounds__(1024, 4) void kmain(
    const unsigned char* __restrict__ En8, const float* __restrict__ W,
    float* __restrict__ psum)
{
  __shared__ __align__(16) unsigned char Asm[256 * 512];   // 128 KB
  __shared__ __align__(16) unsigned char Bsm[2][8192];     // 16 KB
  __shared__ float rowsum[128];
  __shared__ float smemS[2][256];

  int bid = blockIdx.x;
  int xcd = bid & 7;
  int panel = (bid >> 3) & 1;
  int grp = bid >> 4;                        // 0..15
  int cg = xcd | (grp << 3);                 // 0..127

  int tid = threadIdx.x;
  int w = tid >> 6, l = tid & 63;
  int wr = w >> 1, wc = w & 1;               // 8 row-waves x 2 col-waves
  int cl = l & 31, hi = l >> 5;
  int bcls = tid >> 3, bs3 = tid & 7;        // B staging: class(0..127), 32B k-seg

  int nt = (NT128 - cg + 127) >> 7;          // 7 (cg<14) else 6
  int nph = nt * 8;

  // ---- stage A panel once: pure linear glds (source pre-swizzled) ----
#pragma unroll
  for (int i = 0; i < 8; ++i) {
    int base = i * 16384 + w * 1024;
    __builtin_amdgcn_global_load_lds(
        (const __attribute__((address_space(1))) void*)(En8 + panel * 131072 + base + l * 16),
        (__attribute__((address_space(3))) void*)(&Asm[base]), 16, 0, 0);
  }

  float ssq = 0.f;
  const int boff = (bcls >> 6) * 4096
                 + ((bs3 & 1) * 2 + (bs3 >> 2)) * 1024
                 + (bcls & 63) * 16 + ((bs3 >> 1) & 1) * 8;

  f32x4 Ra0, Ra1, Rb0, Rb1;
  auto loadB = [&](int q, f32x4& v0, f32x4& v1) {
    int cls = (cg + ((q >> 3) << 7)) * 128 + bcls;
    if (cls >= NCLS) cls = NCLS - 1;
    const float* p = W + (size_t)cls * EMBED + (q & 7) * 64 + bs3 * 8;
    v0 = *(const f32x4*)p;
    v1 = *(const f32x4*)(p + 4);
  };
  auto writeB = [&](int buf, f32x4 v0, f32x4 v1) {
    float x0 = v0.x*128.f, x1 = v0.y*128.f, x2 = v0.z*128.f, x3 = v0.w*128.f;
    float x4 = v1.x*128.f, x5 = v1.y*128.f, x6 = v1.z*128.f, x7 = v1.w*128.f;
    ssq += x0*x0 + x1*x1 + x2*x2 + x3*x3 + x4*x4 + x5*x5 + x6*x6 + x7*x7;
    uint2 pk;
    pk.x = cvt4(x0, x1, x2, x3);
    pk.y = cvt4(x4, x5, x6, x7);
    *(uint2*)(&Bsm[buf][boff]) = pk;
  };

  f32x16 acc0, acc1, S;
#pragma unroll
  for (int e = 0; e < 16; ++e) { acc0[e] = 0.f; acc1[e] = 0.f; S[e] = 0.f; }

  const unsigned char* Abase = &Asm[(wr * 32 + cl) * 512];
  const unsigned char* Bc0 = &Bsm[0][wc * 4096 + (hi * 2) * 1024 + cl * 16];
  const unsigned char* Bc1 = &Bsm[1][wc * 4096 + (hi * 2) * 1024 + cl * 16];

  auto compute = [&](const unsigned char* bb, int pt) {
    int t0 = pt * 2;
    i64x2 a0 = *(const i64x2*)(Abase + ((((hi << 4) | t0)       ^ cl) << 4));
    i64x2 a1 = *(const i64x2*)(Abase + ((((hi << 4) | (t0 + 1)) ^ cl) << 4));
    i64x2 b0 = *(const i64x2*)(bb);
    i64x2 b1 = *(const i64x2*)(bb + 1024);
    i64x2 c0 = *(const i64x2*)(bb + 512);
    i64x2 c1 = *(const i64x2*)(bb + 1024 + 512);
    acc0 = __builtin_amdgcn_mfma_f32_32x32x16_fp8_fp8(a0[0], b0[0], acc0, 0, 0, 0);
    acc0 = __builtin_amdgcn_mfma_f32_32x32x16_fp8_fp8(a0[1], b0[1], acc0, 0, 0, 0);
    acc0 = __builtin_amdgcn_mfma_f32_32x32x16_fp8_fp8(a1[0], b1[0], acc0, 0, 0, 0);
    acc0 = __builtin_amdgcn_mfma_f32_32x32x16_fp8_fp8(a1[1], b1[1], acc0, 0, 0, 0);
    acc1 = __builtin_amdgcn_mfma_f32_32x32x16_fp8_fp8(a0[0], c0[0], acc1, 0, 0, 0);
    acc1 = __builtin_amdgcn_mfma_f32_32x32x16_fp8_fp8(a0[1], c0[1], acc1, 0, 0, 0);
    acc1 = __builtin_amdgcn_mfma_f32_32x32x16_fp8_fp8(a1[0], c1[0], acc1, 0, 0, 0);
    acc1 = __builtin_amdgcn_mfma_f32_32x32x16_fp8_fp8(a1[1], c1[1], acc1, 0, 0, 0);
  };

  auto ssqred = [&]() {
    float sq = ssq;
    sq += __shfl_xor(sq, 1); sq += __shfl_xor(sq, 2); sq += __shfl_xor(sq, 4);
    if (bs3 == 0) rowsum[bcls] = sq;
    ssq = 0.f;
  };

  auto epilogue = [&](int T) {
    int base = (cg + (T << 7)) * 128 + wc * 64;
    float rs0 = fmaxf(rowsum[wc * 64 + cl], 1e-30f);
    float rs1 = fmaxf(rowsum[wc * 64 + 32 + cl], 1e-30f);
    float rn0 = 4.0f / sqrtf(rs0);
    float rn1 = 4.0f / sqrtf(rs1);
    float vm0 = (base + cl < NCLS) ? 1.0f : 0.0f;
    float vm1 = (base + 32 + cl < NCLS) ? 1.0f : 0.0f;
#pragma unroll
    for (int e = 0; e < 16; ++e) {
      float u0 = __expf(fmaf(acc0[e], rn0, -64.0f));
      float u1 = __expf(fmaf(acc1[e], rn1, -64.0f));
      S[e] = fmaf(u0, vm0, fmaf(u1, vm1, S[e]));
      acc0[e] = 0.f; acc1[e] = 0.f;
    }
  };

  // ---- prologue: stage phases 0,1; regs hold phases 2,3 ----
  loadB(0, Ra0, Ra1); loadB(1, Rb0, Rb1);
  writeB(0, Ra0, Ra1); writeB(1, Rb0, Rb1);
  loadB(2, Ra0, Ra1); loadB(3, Rb0, Rb1);
  asm volatile("s_waitcnt vmcnt(0)" ::: "memory");   // A + Bsm[0/1] staged
  BARRIER();

  for (int p = 0; p < nph; p += 2) {
    // -------- even phase --------
    compute(Bc0, p & 7);
    BARRIER();                                  // readers done with Bsm[0]
    if (p + 2 < nph) writeB(0, Ra0, Ra1);       // stage phase p+2
    if (p + 4 < nph) loadB(p + 4, Ra0, Ra1);
    // -------- odd phase --------
    int po = p + 1;
    compute(Bc1, po & 7);
    if ((po & 7) == 7) epilogue(po >> 3);       // rowsum fenced one barrier ago
    BARRIER();                                  // readers done with Bsm[1]
    if (po + 2 < nph) writeB(1, Rb0, Rb1);      // stage phase po+2
    if (po + 4 < nph) loadB(po + 4, Rb0, Rb1);
    if (((po + 2) & 7) == 7) ssqred();          // tile's 8 chunks all staged
  }

  // ---- fold S across the 32 class-lanes; combine the 2 col-waves ----
#pragma unroll
  for (int e = 0; e < 16; ++e) {
    float v = S[e];
    v += __shfl_xor(v, 1); v += __shfl_xor(v, 2); v += __shfl_xor(v, 4);
    v += __shfl_xor(v, 8); v += __shfl_xor(v, 16);
    S[e] = v;
  }
  __syncthreads();
  if (cl == 0) {
#pragma unroll
    for (int e = 0; e < 16; ++e) {
      int row = wr * 32 + (e & 3) + 8 * (e >> 2) + 4 * hi;
      smemS[wc][row] = S[e];
    }
  }
  __syncthreads();
  if (tid < 256) psum[bid * 256 + tid] = smemS[0][tid] + smemS[1][tid];
}

// ---------------- K4: final combine (kred folded) + label adjust + NLL mean ----
__global__ void kfinal(const float* __restrict__ psum, const float* __restrict__ lcos,
                       const float* __restrict__ lphi, float* __restrict__ out)
{
  int tid = threadIdx.x;         // 512 = one thread per batch row
  int panel = tid >> 8, rl = tid & 255;
  float S = 0.f;
#pragma unroll
  for (int grp = 0; grp < 16; ++grp) {
#pragma unroll
    for (int x = 0; x < 8; ++x) {
      int b = x | (panel << 3) | (grp << 4);
      S += psum[b * 256 + rl];
    }
  }
  float lc = lcos[tid], lp = lphi[tid];
  S = S - __expf(lc - 64.f) + __expf(lp - 64.f);
  float nll = 64.f + __logf(S) - lp;
#pragma unroll
  for (int d = 1; d < 64; d <<= 1) nll += __shfl_xor(nll, d);
  __shared__ float sm[8];
  if ((tid & 63) == 0) sm[tid >> 6] = nll;
  __syncthreads();
  if (tid == 0) {
    float t = 0.f;
    for (int k = 0; k < 8; ++k) t += sm[k];
    out[0] = t * (1.0f / 512.0f);
  }
}

extern "C" void kernel_launch(void* const* d_in, const int* in_sizes, int n_in,
                              void* d_out, int out_size, void* d_ws, size_t ws_size,
                              hipStream_t stream)
{
  const float* E      = (const float*)d_in[0];
  const int*   labels = (const int*)d_in[1];
  const float* W      = (const float*)d_in[2];
  float* out = (float*)d_out;

  char* ws = (char*)d_ws;
  unsigned char* En8 = (unsigned char*)ws;              // 512*512 = 262144 B
  float* psum = (float*)(ws + 262144);                  // 256*256*4 = 262144 B
  float* lcos = (float*)(ws + 524288);                  // 2048 B
  float* lphi = lcos + BATCH;                           // 2048 B

  knorm_e<<<BATCH, 64, 0, stream>>>(E, En8);
  klabel <<<64, 512, 0, stream>>>(E, W, labels, lcos, lphi);
  kmain  <<<NBLK, 1024, 0, stream>>>(En8, W, psum);
  kfinal <<<1, 512, 0, stream>>>(psum, lcos, lphi, out);
}